// Round 8
// baseline (113.031 us; speedup 1.0000x reference)
//
#include <hip/hip_runtime.h>

typedef __attribute__((ext_vector_type(4))) float f32x4;
typedef __attribute__((ext_vector_type(16))) float f32x16;
typedef __attribute__((ext_vector_type(8))) _Float16 f16x8;
typedef __attribute__((ext_vector_type(2))) __fp16 fp16x2_raw;
typedef __attribute__((ext_vector_type(4))) unsigned int u32x4;
typedef __attribute__((ext_vector_type(2))) unsigned int u32x2;

#define MFMA_F16(a, b, c) __builtin_amdgcn_mfma_f32_16x16x32_f16((a), (b), (c), 0, 0, 0)
#define MFMA32(a, b, c) __builtin_amdgcn_mfma_f32_32x32x16_f16((a), (b), (c), 0, 0, 0)

__device__ __forceinline__ unsigned int pkrtz(float a, float b) {
  union { fp16x2_raw h; unsigned int u; } v;
  v.h = __builtin_amdgcn_cvt_pkrtz(a, b);
  return v.u;
}

typedef const __attribute__((address_space(1))) unsigned int ga_u32_t;
typedef __attribute__((address_space(3))) unsigned int ls_u32_t;
__device__ __forceinline__ void gload16(const void* g, void* l) {
  __builtin_amdgcn_global_load_lds((ga_u32_t*)g, (ls_u32_t*)l, 16, 0, 0);
}

// ---------- prep: transpose f32 [512][N] -> fp16 [N][512] ----------
__global__ __launch_bounds__(256)
void k_prep_w(const float* __restrict__ in, _Float16* __restrict__ out, int N) {
  __shared__ float t[64][65];
  const int tid = threadIdx.x;
  const int bn = blockIdx.x * 64, bk = blockIdx.y * 64;
  #pragma unroll
  for (int it = 0; it < 16; ++it) {
    int idx = it * 256 + tid;
    int kk = idx >> 6, nn = idx & 63;
    t[kk][nn] = in[(bk + kk) * N + bn + nn];
  }
  __syncthreads();
  #pragma unroll
  for (int it = 0; it < 16; ++it) {
    int idx = it * 256 + tid;
    int nn = idx >> 6, kk = idx & 63;
    out[(bn + nn) * 512 + bk + kk] = (_Float16)t[kk][nn];
  }
}

// ---------- GEMM1: qkv = x @ w_qkv (x f32 converted in staging), fused RoPE ----------
__global__ __launch_bounds__(256, 3)
void k_gemm_qkv(const float* __restrict__ x,
                const _Float16* __restrict__ wT,
                const int* __restrict__ pos_h,
                const int* __restrict__ pos_w,
                _Float16* __restrict__ qh,
                _Float16* __restrict__ kh,
                _Float16* __restrict__ vT) {
  __shared__ char As[8192], Bs[8192];
  const int tid = threadIdx.x;
  const int lane = tid & 63, w = tid >> 6;
  const int lr = lane & 15, g = lane >> 4;
  const int m0 = blockIdx.y * 128;
  const int n0 = blockIdx.x * 128;
  const int wr = w >> 1, wc = w & 1;

  f32x4 acc[4][4];
  #pragma unroll
  for (int i = 0; i < 4; ++i)
    #pragma unroll
    for (int j = 0; j < 4; ++j) acc[i][j] = (f32x4){0.f, 0.f, 0.f, 0.f};

  for (int kt = 0; kt < 16; ++kt) {
    const int k0 = kt * 32;
    __syncthreads();
    #pragma unroll
    for (int it = 0; it < 2; ++it) {
      int idx = it * 256 + tid;
      int r = idx >> 2, ch = idx & 3;
      const float* px = x + (size_t)(m0 + r) * 512 + k0 + ch * 8;
      f32x4 v0 = *(const f32x4*)px;
      f32x4 v1 = *(const f32x4*)(px + 4);
      u32x4 d;
      d.x = pkrtz(v0[0], v0[1]); d.y = pkrtz(v0[2], v0[3]);
      d.z = pkrtz(v1[0], v1[1]); d.w = pkrtz(v1[2], v1[3]);
      *(u32x4*)(As + (((r << 6) + (ch << 4)) ^ ((r & 7) << 4))) = d;
    }
    #pragma unroll
    for (int it = 0; it < 2; ++it) {
      int idx = it * 256 + tid;
      int r = idx >> 2, ch = idx & 3;
      u32x4 d = *(const u32x4*)(wT + (n0 + r) * 512 + k0 + ch * 8);
      *(u32x4*)(Bs + (((r << 6) + (ch << 4)) ^ ((r & 7) << 4))) = d;
    }
    __syncthreads();

    f16x8 af[4], bf[4];
    #pragma unroll
    for (int mi = 0; mi < 4; ++mi) {
      int r = 64 * wr + 16 * mi + lr;
      af[mi] = *(const f16x8*)(As + (((r << 6) + (g << 4)) ^ ((r & 7) << 4)));
    }
    #pragma unroll
    for (int nj = 0; nj < 4; ++nj) {
      int r = 64 * wc + 16 * nj + lr;
      bf[nj] = *(const f16x8*)(Bs + (((r << 6) + (g << 4)) ^ ((r & 7) << 4)));
    }
    __builtin_amdgcn_s_setprio(1);
    #pragma unroll
    for (int mi = 0; mi < 4; ++mi)
      #pragma unroll
      for (int nj = 0; nj < 4; ++nj)
        acc[mi][nj] = MFMA_F16(af[mi], bf[nj], acc[mi][nj]);
    __builtin_amdgcn_s_setprio(0);
  }

  // epilogue: RoPE (q,k) + permuted-transpose write (v)
  #pragma unroll
  for (int mi = 0; mi < 4; ++mi) {
    const int r0f = m0 + 64 * wr + 16 * mi + 4 * g;
    const int n = r0f >> 11;
    const int t = r0f & 2047;
    #pragma unroll
    for (int nj = 0; nj < 4; ++nj) {
      const int c = n0 + 64 * wc + 16 * nj + lr;
      const int mat = c >> 9;          // 0=q 1=k 2=v
      const int hh = (c >> 6) & 7;
      const int dh = c & 63;
      f32x4 v = acc[mi][nj];
      if (mat == 2) {
        // V column permutation for 32x32 PV: swap bits 2<->3 of t (self-inverse)
        int tperm = (t & ~12) | (((t >> 2) & 1) << 3) | (((t >> 3) & 1) << 2);
        u32x2 pk2;
        pk2.x = pkrtz(v[0], v[1]);
        pk2.y = pkrtz(v[2], v[3]);
        *(u32x2*)(vT + (size_t)((n * 8 + hh) * 64 + dh) * 2048 + tperm) = pk2;
      } else {
        const int p = (dh & 31) >> 1;
        const float freq = exp2f((float)p * -0.8304820237218405f);  // theta^(-p/16)
        const int odd = lane & 1;
        const int* posArr = (dh < 32) ? pos_h : pos_w;
        _Float16* dst = mat ? kh : qh;
        // q: fold 1/sqrt(64) AND log2(e) (softmax uses exp2)
        const float scale = mat ? 1.0f : 0.125f * 1.44269504088896f;
        #pragma unroll
        for (int i = 0; i < 4; ++i) {
          float val = v[i];
          float oth = __shfl_xor(val, 1);
          float ang = (float)posArr[t + i] * freq;
          float sv, cv;
          __sincosf(ang, &sv, &cv);
          float x1 = odd ? oth : val;
          float x2 = odd ? val : oth;
          float res = odd ? (x1 * sv + x2 * cv) : (x1 * cv - x2 * sv);
          dst[(size_t)((n * 8 + hh) * 2048 + t + i) * 64 + dh] = (_Float16)(res * scale);
        }
      }
    }
  }
}

// ---------- flash attention: 32x32 MFMA, 8 waves, 256 q-rows/block ----------
// grid 256: qt=(bid>>3)&7, nh=(bid&7)+8*(bid>>6)  (XCD-chunked: 4 heads/XCD)
__global__ __launch_bounds__(512, 2)
void k_attn(const _Float16* __restrict__ qh,
            const _Float16* __restrict__ kh,
            const _Float16* __restrict__ vp,
            _Float16* __restrict__ o_flat) {
  __shared__ char Ks[2][16384];  // dbuf x [2 sub][64 s][64 dh] f16, pre-swz ^((s&7)<<4)
  __shared__ char Vs[2][16384];  // dbuf x [2 sub][64 dh][64 s-perm] f16, pre-swz ^((dh&7)<<4)
  const int tid = threadIdx.x, lane = tid & 63, w = tid >> 6;  // 8 waves
  const int q5 = lane & 31, hi = lane >> 5;
  const int bid = blockIdx.x;
  const int qt = (bid >> 3) & 7;
  const int nh = (bid & 7) + 8 * (bid >> 6);

  // Q fragments (B-operand of swapped QK): col=q=lane&31, k-rows 8*hi+0..7 per kg
  f16x8 qf[4];
  const _Float16* qbase = qh + ((size_t)nh * 2048 + qt * 256 + w * 32 + q5) * 64;
  #pragma unroll
  for (int kg = 0; kg < 4; ++kg)
    qf[kg] = *(const f16x8*)(qbase + kg * 16 + hi * 8);

  f32x16 oacc[2];
  float lacc = 0.f;
  #pragma unroll
  for (int d = 0; d < 2; ++d)
    #pragma unroll
    for (int i = 0; i < 16; ++i) oacc[d][i] = 0.f;

  const _Float16* kb = kh + (size_t)nh * 2048 * 64;
  const _Float16* vb = vp + (size_t)nh * 64 * 2048;

  // staging: each wave stages 1KB of K and 1KB of V per 64-s sub-tile
  const int rr = lane >> 3, cc = lane & 7;
  const int srow = w * 8 + rr;                 // row 0..63 within sub-tile
  const _Float16* ksrc = kb + (size_t)srow * 64 + ((cc ^ (srow & 7)) << 3);
  const _Float16* vsrc = vb + (size_t)srow * 2048 + ((cc ^ (srow & 7)) << 3);
  auto stage = [&](int b, int kt2) {
    #pragma unroll
    for (int h = 0; h < 2; ++h) {
      int kt = kt2 * 2 + h;
      gload16(ksrc + (size_t)kt * 4096, Ks[b] + h * 8192 + w * 1024);
      gload16(vsrc + (size_t)kt * 64,   Vs[b] + h * 8192 + w * 1024);
    }
  };

  stage(0, 0);  // prologue: 4 loads in flight

  for (int kt2 = 0; kt2 < 16; ++kt2) {
    const int cur = kt2 & 1;
    asm volatile("" ::: "memory");
    __builtin_amdgcn_s_barrier();          // A: all waves done reading buf cur^1
    if (kt2 + 1 < 16) {
      stage(cur ^ 1, kt2 + 1);             // issue next phase (4 loads)
      asm volatile("s_waitcnt vmcnt(4)" ::: "memory");  // current phase landed
    } else {
      asm volatile("s_waitcnt vmcnt(0)" ::: "memory");
    }
    __builtin_amdgcn_s_barrier();          // B: current phase visible
    asm volatile("" ::: "memory");

    // S^T = K Q^T  (32x32 tiles; lane owns q=lane&31; init carries -8 bias)
    f32x16 sacc[2][2];
    #pragma unroll
    for (int h = 0; h < 2; ++h)
      #pragma unroll
      for (int sb = 0; sb < 2; ++sb)
        #pragma unroll
        for (int i = 0; i < 16; ++i) sacc[h][sb][i] = -8.f;

    __builtin_amdgcn_s_setprio(1);
    #pragma unroll
    for (int h = 0; h < 2; ++h) {
      const char* Kb = Ks[cur] + h * 8192;
      #pragma unroll
      for (int sb = 0; sb < 2; ++sb) {
        int row = sb * 32 + q5;
        int rb = row << 7, sw = (row & 7) << 4;
        #pragma unroll
        for (int kg = 0; kg < 4; ++kg) {
          f16x8 kf = *(const f16x8*)(Kb + (rb + ((kg * 32 + hi * 16) ^ sw)));
          sacc[h][sb] = MFMA32(kf, qf[kg], sacc[h][sb]);
        }
      }
    }
    __builtin_amdgcn_s_setprio(0);

    // per sub-tile: fixed-M softmax (VALU) then PV (MFMA) -- SM(h=1) overlaps PV(h=0)
    #pragma unroll
    for (int h = 0; h < 2; ++h) {
      const char* Vb = Vs[cur] + h * 8192;
      float rs = 0.f;
      #pragma unroll
      for (int sb = 0; sb < 2; ++sb)
        #pragma unroll
        for (int i = 0; i < 16; ++i) {
          float e = exp2f(sacc[h][sb][i]);
          sacc[h][sb][i] = e;
          rs += e;
        }
      lacc += rs;

      __builtin_amdgcn_s_setprio(1);
      #pragma unroll
      for (int sb = 0; sb < 2; ++sb)
        #pragma unroll
        for (int m = 0; m < 2; ++m) {
          union { unsigned int u[4]; f16x8 hh; } pb;
          #pragma unroll
          for (int i = 0; i < 4; ++i)
            pb.u[i] = pkrtz(sacc[h][sb][8 * m + 2 * i], sacc[h][sb][8 * m + 2 * i + 1]);
          #pragma unroll
          for (int d = 0; d < 2; ++d) {
            int row = d * 32 + q5;
            f16x8 vf = *(const f16x8*)(Vb + ((row << 7) +
                        ((sb * 64 + m * 32 + hi * 16) ^ ((row & 7) << 4))));
            oacc[d] = MFMA32(vf, pb.hh, oacc[d]);
          }
        }
      __builtin_amdgcn_s_setprio(0);
    }
  }

  // epilogue: l across lane halves, normalize, write fp16 o [8192][512]
  float l = lacc + __shfl_xor(lacc, 32);
  float inv = 1.0f / l;
  const int row = qt * 256 + w * 32 + q5;
  const int n = nh >> 3, hh = nh & 7;
  _Float16* orow = o_flat + ((size_t)(n * 2048 + row)) * 512 + hh * 64;
  #pragma unroll
  for (int d = 0; d < 2; ++d)
    #pragma unroll
    for (int r4 = 0; r4 < 4; ++r4) {
      int dh0 = d * 32 + 8 * r4 + 4 * hi;
      u32x2 p2;
      p2.x = pkrtz(oacc[d][4 * r4] * inv,     oacc[d][4 * r4 + 1] * inv);
      p2.y = pkrtz(oacc[d][4 * r4 + 2] * inv, oacc[d][4 * r4 + 3] * inv);
      *(u32x2*)(orow + dh0) = p2;
    }
}

// ---------- GEMM3: out = o @ w_proj + b (fp16 -> f32) ----------
__global__ __launch_bounds__(256, 3)
void k_gemm_proj(const _Float16* __restrict__ o_flat,
                 const _Float16* __restrict__ wpT,
                 const float* __restrict__ bias,
                 float* __restrict__ out) {
  __shared__ char As[8192], Bs[8192];
  const int tid = threadIdx.x;
  const int lane = tid & 63, w = tid >> 6;
  const int lr = lane & 15, g = lane >> 4;
  const int m0 = blockIdx.y * 128;
  const int n0 = blockIdx.x * 128;
  const int wr = w >> 1, wc = w & 1;

  f32x4 acc[4][4];
  #pragma unroll
  for (int i = 0; i < 4; ++i)
    #pragma unroll
    for (int j = 0; j < 4; ++j) acc[i][j] = (f32x4){0.f, 0.f, 0.f, 0.f};

  for (int kt = 0; kt < 16; ++kt) {
    const int k0 = kt * 32;
    __syncthreads();
    #pragma unroll
    for (int it = 0; it < 2; ++it) {
      int idx = it * 256 + tid;
      int r = idx >> 2, ch = idx & 3;
      u32x4 d = *(const u32x4*)(o_flat + (m0 + r) * 512 + k0 + ch * 8);
      *(u32x4*)(As + (((r << 6) + (ch << 4)) ^ ((r & 7) << 4))) = d;
    }
    #pragma unroll
    for (int it = 0; it < 2; ++it) {
      int idx = it * 256 + tid;
      int r = idx >> 2, ch = idx & 3;
      u32x4 d = *(const u32x4*)(wpT + (n0 + r) * 512 + k0 + ch * 8);
      *(u32x4*)(Bs + (((r << 6) + (ch << 4)) ^ ((r & 7) << 4))) = d;
    }
    __syncthreads();

    f16x8 af[4], bf[4];
    #pragma unroll
    for (int mi = 0; mi < 4; ++mi) {
      int r = 64 * wr + 16 * mi + lr;
      af[mi] = *(const f16x8*)(As + (((r << 6) + (g << 4)) ^ ((r & 7) << 4)));
    }
    #pragma unroll
    for (int nj = 0; nj < 4; ++nj) {
      int r = 64 * wc + 16 * nj + lr;
      bf[nj] = *(const f16x8*)(Bs + (((r << 6) + (g << 4)) ^ ((r & 7) << 4)));
    }
    __builtin_amdgcn_s_setprio(1);
    #pragma unroll
    for (int mi = 0; mi < 4; ++mi)
      #pragma unroll
      for (int nj = 0; nj < 4; ++nj)
        acc[mi][nj] = MFMA_F16(af[mi], bf[nj], acc[mi][nj]);
    __builtin_amdgcn_s_setprio(0);
  }

  #pragma unroll
  for (int mi = 0; mi < 4; ++mi) {
    int r0f = m0 + 64 * wr + 16 * mi + 4 * g;
    #pragma unroll
    for (int nj = 0; nj < 4; ++nj) {
      int c = n0 + 64 * wc + 16 * nj + lr;
      float b = bias[c];
      #pragma unroll
      for (int i = 0; i < 4; ++i)
        out[(size_t)(r0f + i) * 512 + c] = acc[mi][nj][i] + b;
    }
  }
}

extern "C" void kernel_launch(void* const* d_in, const int* in_sizes, int n_in,
                              void* d_out, int out_size, void* d_ws, size_t ws_size,
                              hipStream_t stream) {
  const float* x      = (const float*)d_in[0];
  const int*   pos_h  = (const int*)d_in[1];
  const int*   pos_w  = (const int*)d_in[2];
  const float* w_qkv  = (const float*)d_in[3];
  const float* w_proj = (const float*)d_in[4];
  const float* b_proj = (const float*)d_in[5];
  float* out = (float*)d_out;

  char* ws = (char*)d_ws;
  size_t off = 0;
  auto alloc = [&](size_t bytes) {
    char* p = ws + off;
    off += (bytes + 1023) & ~(size_t)1023;
    return p;
  };
  _Float16* qh     = (_Float16*)alloc((size_t)32 * 2048 * 64 * 2);
  _Float16* kh     = (_Float16*)alloc((size_t)32 * 2048 * 64 * 2);
  _Float16* vT     = (_Float16*)alloc((size_t)32 * 2048 * 64 * 2);
  _Float16* o_flat = (_Float16*)alloc((size_t)8192 * 512 * 2);
  _Float16* wqT    = (_Float16*)alloc((size_t)1536 * 512 * 2);
  _Float16* wpT    = (_Float16*)alloc((size_t)512 * 512 * 2);

  hipLaunchKernelGGL(k_prep_w, dim3(24, 8), dim3(256), 0, stream, w_qkv, wqT, 1536);
  hipLaunchKernelGGL(k_prep_w, dim3(8, 8), dim3(256), 0, stream, w_proj, wpT, 512);
  hipLaunchKernelGGL(k_gemm_qkv, dim3(12, 64), dim3(256), 0, stream,
                     x, wqT, pos_h, pos_w, qh, kh, vT);
  hipLaunchKernelGGL(k_attn, dim3(256), dim3(512), 0, stream, qh, kh, vT, o_flat);
  hipLaunchKernelGGL(k_gemm_proj, dim3(4, 64), dim3(256), 0, stream, o_flat, wpT, b_proj, out);
}